// Round 1
// baseline (519.641 us; speedup 1.0000x reference)
//
#include <hip/hip_runtime.h>

// Problem: B=1024 batches, N=256 nodes, F=63 in-features, D=64 hidden.
// Only node-0 readout is needed => layer 2 is a single row per batch, and
// layer 1 is needed only at node 0's neighbors (nonzeros of adj[b,0,:]).
// One block per batch; vec[b] + w1 staged in LDS; adj rows prefetched.

#define NB 1024
#define NN 256
#define FD 63
#define DM 64

__launch_bounds__(256, 1)
__global__ void gnn_node0_fused(const float* __restrict__ adj,
                                const float* __restrict__ vec,
                                const float* __restrict__ w1_rel,
                                const float* __restrict__ w1_root,
                                const float* __restrict__ b1,
                                const float* __restrict__ w2_rel,
                                const float* __restrict__ w2_root,
                                const float* __restrict__ b2,
                                const float* __restrict__ wf,
                                const float* __restrict__ bf,
                                float* __restrict__ out)
{
    __shared__ float s_vec[NN * FD];      // 63 KB  vec[b], row-major [node][feat]
    __shared__ float s_w1rel[FD * DM];    // 15.75 KB
    __shared__ float s_w1root[FD * DM];   // 15.75 KB
    __shared__ float s_row0[NN];          // adj[b,0,:]
    __shared__ float s_row[2][NN];        // double-buffered current adj row
    __shared__ float s_part[4][DM];       // cross-wave partials
    __shared__ float s_agg[DM];           // agg_j (63 used)
    __shared__ float s_x0[DM];            // x[b,0]
    __shared__ float s_accY[DM];          // sum_j a0j * x_j
    __shared__ int   s_nbr[NN];           // neighbor indices (unordered)
    __shared__ float s_a0[NN];            // adj[b,0,nbr]
    __shared__ float s_r[DM];
    __shared__ int   s_cnt;

    const int b = blockIdx.x;
    const int t = threadIdx.x;
    const float* adj_b = adj + (size_t)b * NN * NN;
    const float* vec_b = vec + (size_t)b * NN * FD;

    if (t == 0) s_cnt = 0;
    if (t < DM) { s_accY[t] = 0.f; s_x0[t] = 0.f; }

    s_row0[t] = adj_b[t];                 // adj[b,0,:]
    __syncthreads();

    // Unordered neighbor compaction (order-independent accumulation).
    {
        float a = s_row0[t];
        if (a != 0.f) {
            int idx = atomicAdd(&s_cnt, 1);
            s_nbr[idx] = t;
            s_a0[idx]  = a;
        }
    }
    // Stage vec[b] and layer-1 weights in LDS (coalesced).
    for (int i = t; i < NN * FD; i += 256) s_vec[i] = vec_b[i];
    for (int i = t; i < FD * DM; i += 256) { s_w1rel[i] = w1_rel[i]; s_w1root[i] = w1_root[i]; }
    __syncthreads();

    const int cnt = s_cnt;                // always >=1 (self-loop at node 0)
    const float rb1 = (t < DM) ? b1[t] : 0.f;

    // Prefetch first selected adj row.
    int cur = 0;
    s_row[0][t] = adj_b[s_nbr[0] * NN + t];
    __syncthreads();

    const int f = t & 63;                 // feature/output lane
    const int q = t >> 6;                 // wave index (4 waves)

    for (int i = 0; i < cnt; ++i) {
        const int j = s_nbr[i];
        // Prefetch next row; store into the other buffer at end of iter so
        // the ~700cy HBM latency hides under this iteration's compute.
        float nxt = 0.f;
        if (i + 1 < cnt) nxt = adj_b[s_nbr[i + 1] * NN + t];

        // Stage 1: agg[f] = sum_k adjrow[k] * vec[k][f]; each wave does a
        // 64-wide k-quarter. s_vec reads are lane-consecutive (<=2-way bank).
        float p1 = 0.f;
        if (f < FD) {
            const int k0 = q * 64;
            #pragma unroll 8
            for (int k = k0; k < k0 + 64; ++k)
                p1 += s_row[cur][k] * s_vec[k * FD + f];
        }
        s_part[q][f] = (f < FD) ? p1 : 0.f;
        __syncthreads();
        if (t < DM) s_agg[t] = s_part[0][t] + s_part[1][t] + s_part[2][t] + s_part[3][t];
        __syncthreads();

        // Stage 2: x_j[d] = relu(agg @ w1_rel + vec[j] @ w1_root + b1)[d],
        // f-range split across the 4 waves.
        float p2 = 0.f;
        {
            const int f0 = q * 16;
            const int f1 = (q == 3) ? FD : (f0 + 16);
            for (int ff = f0; ff < f1; ++ff)
                p2 += s_agg[ff] * s_w1rel[ff * DM + f]
                    + s_vec[j * FD + ff] * s_w1root[ff * DM + f];
        }
        s_part[q][f] = p2;
        __syncthreads();
        if (t < DM) {
            float x = fmaxf(s_part[0][t] + s_part[1][t] + s_part[2][t] + s_part[3][t] + rb1, 0.f);
            s_accY[t] += s_a0[i] * x;     // layer-2 row-0 aggregation
            if (j == 0) s_x0[t] = x;
        }
        s_row[cur ^ 1][t] = nxt;          // commit prefetched row
        __syncthreads();
        cur ^= 1;
    }

    // Layer-2 row 0: y0 = relu(accY @ w2_rel + x0 @ w2_root + b2).
    // w2 reads are lane-coalesced and L2-resident (shared across blocks).
    float p3 = 0.f;
    {
        const int f0 = q * 16;
        for (int ff = f0; ff < f0 + 16; ++ff)
            p3 += s_accY[ff] * w2_rel[ff * DM + f]
                + s_x0[ff] * w2_root[ff * DM + f];
    }
    s_part[q][f] = p3;
    __syncthreads();
    if (t < DM) {
        float y = fmaxf(s_part[0][t] + s_part[1][t] + s_part[2][t] + s_part[3][t] + b2[t], 0.f);
        s_r[t] = s_x0[t] + y;
    }
    __syncthreads();
    // Head: out[b,:] = (x0+y0) @ wf + bf   (wf is [64,2] row-major)
    if (t < 2) {
        float acc = bf[t];
        for (int d = 0; d < DM; ++d) acc += s_r[d] * wf[d * 2 + t];
        out[b * 2 + t] = acc;
    }
}

extern "C" void kernel_launch(void* const* d_in, const int* in_sizes, int n_in,
                              void* d_out, int out_size, void* d_ws, size_t ws_size,
                              hipStream_t stream) {
    const float* adj     = (const float*)d_in[0];
    const float* vec     = (const float*)d_in[1];
    const float* w1_rel  = (const float*)d_in[2];
    const float* w1_root = (const float*)d_in[3];
    const float* b1      = (const float*)d_in[4];
    const float* w2_rel  = (const float*)d_in[5];
    const float* w2_root = (const float*)d_in[6];
    const float* b2      = (const float*)d_in[7];
    const float* wf      = (const float*)d_in[8];
    const float* bf      = (const float*)d_in[9];
    float* out = (float*)d_out;

    gnn_node0_fused<<<NB, 256, 0, stream>>>(adj, vec, w1_rel, w1_root, b1,
                                            w2_rel, w2_root, b2, wf, bf, out);
}

// Round 3
// 480.374 us; speedup vs baseline: 1.0817x; 1.0817x over previous
//
#include <hip/hip_runtime.h>

// B=1024, N=256, F=63, D=64. Only node-0 readout matters:
//   out = (x[:,0] + y[:,0]) @ wf + bf
// y[:,0] needs adj row 0's ~14 neighbors' x rows; each x row needs one adj row.
// v2 (resubmit; round-2 bench was an infra failure): sparse stage-1 (ballot
// compaction of adj rows), wave-parallel neighbor loop with NO barriers (shfl
// broadcasts), small LDS (w1 only) -> 4 blocks/CU, double-buffered adj-row
// prefetch.

#define NB 1024
#define NN 256
#define FD 63
#define DM 64

__launch_bounds__(256, 4)
__global__ void gnn_node0_fused(const float* __restrict__ adj,
                                const float* __restrict__ vec,
                                const float* __restrict__ w1_rel,
                                const float* __restrict__ w1_root,
                                const float* __restrict__ b1,
                                const float* __restrict__ w2_rel,
                                const float* __restrict__ w2_root,
                                const float* __restrict__ b2,
                                const float* __restrict__ wf,
                                const float* __restrict__ bf,
                                float* __restrict__ out)
{
    __shared__ float s_w1rel[FD * DM];    // 15.75 KB
    __shared__ float s_w1root[FD * DM];   // 15.75 KB
    __shared__ int   s_nbr[NN];
    __shared__ float s_a0[NN];
    __shared__ float s_pA[4][DM];         // cross-wave partials (accY)
    __shared__ float s_pB[4][DM];         // cross-wave partials (x0)
    __shared__ float s_rA[DM];            // reduced accY
    __shared__ float s_rB[DM];            // reduced x0
    __shared__ float s_r[DM];
    __shared__ int   s_cnt;

    const int b    = blockIdx.x;
    const int t    = threadIdx.x;
    const int lane = t & 63;
    const int q    = t >> 6;
    const float* adj_b = adj + (size_t)b * NN * NN;
    const float* vec_b = vec + (size_t)b * NN * FD;

    if (t == 0) s_cnt = 0;
    __syncthreads();

    // Compact nonzeros of adj[b,0,:] (order-independent accumulation later).
    {
        float a = adj_b[t];
        if (a != 0.f) {
            int idx = atomicAdd(&s_cnt, 1);
            s_nbr[idx] = t;
            s_a0[idx]  = a;
        }
    }
    // Stage layer-1 weights in LDS (float4-vectorized, coalesced).
    {
        const float4* wr = (const float4*)w1_rel;
        const float4* wo = (const float4*)w1_root;
        float4* sr = (float4*)s_w1rel;
        float4* so = (float4*)s_w1root;
        for (int i = t; i < FD * DM / 4; i += 256) { sr[i] = wr[i]; so[i] = wo[i]; }
    }
    __syncthreads();

    const int cnt = s_cnt;                 // >=1 (self-loop at node 0)
    const float rb1 = b1[lane];

    float accY = 0.f, x0r = 0.f;

    // Wave-parallel neighbor loop: wave q owns i = q, q+4, ... ; no barriers.
    int i = q;
    int jcur = (i < cnt) ? s_nbr[i] : 0;
    float ac0 = 0.f, ac1 = 0.f, ac2 = 0.f, ac3 = 0.f;
    if (i < cnt) {
        const float* rp = adj_b + (size_t)jcur * NN;
        ac0 = rp[lane]; ac1 = rp[64 + lane]; ac2 = rp[128 + lane]; ac3 = rp[192 + lane];
    }
    while (i < cnt) {
        const int inext = i + 4;
        float an0 = 0.f, an1 = 0.f, an2 = 0.f, an3 = 0.f;
        int jnext = 0;
        if (inext < cnt) {
            jnext = s_nbr[inext];
            const float* rp = adj_b + (size_t)jnext * NN;   // next-row prefetch (HBM)
            an0 = rp[lane]; an1 = rp[64 + lane]; an2 = rp[128 + lane]; an3 = rp[192 + lane];
        }
        const int   j  = jcur;
        const float a0 = s_a0[i];

        // Stage 1 (sparse): agg[f=lane] = sum over nonzero k of row_j.
        float agg = 0.f;
        #pragma unroll
        for (int c = 0; c < 4; ++c) {
            float av_src = (c == 0) ? ac0 : (c == 1) ? ac1 : (c == 2) ? ac2 : ac3;
            unsigned long long m = __ballot(av_src != 0.f);
            while (m) {
                int bit = __builtin_ctzll(m);
                m &= m - 1;
                float av = __shfl(av_src, bit);
                int k = c * 64 + bit;
                float vv = (lane < FD) ? vec_b[k * FD + lane] : 0.f;   // L1/L2 hit
                agg += av * vv;
            }
        }

        // Stage 2: x_j[d=lane] = relu(agg @ w1_rel + vec_j @ w1_root + b1).
        float vj = (lane < FD) ? vec_b[j * FD + lane] : 0.f;
        float accR = 0.f, accO = 0.f;
        #pragma unroll
        for (int ff = 0; ff < FD; ++ff) {
            float af = __shfl(agg, ff);
            float vf = __shfl(vj, ff);
            accR += af * s_w1rel[ff * DM + lane];
            accO += vf * s_w1root[ff * DM + lane];
        }
        float x = fmaxf(accR + accO + rb1, 0.f);
        accY += a0 * x;
        if (j == 0) x0r = x;

        i = inext; jcur = jnext;
        ac0 = an0; ac1 = an1; ac2 = an2; ac3 = an3;
    }

    // Cross-wave reduction of accY and x0.
    s_pA[q][lane] = accY;
    s_pB[q][lane] = x0r;
    __syncthreads();
    if (q == 0) {
        s_rA[lane] = s_pA[0][lane] + s_pA[1][lane] + s_pA[2][lane] + s_pA[3][lane];
        s_rB[lane] = s_pB[0][lane] + s_pB[1][lane] + s_pB[2][lane] + s_pB[3][lane];
    }
    __syncthreads();

    // Layer-2 row 0: y0 = relu(accY @ w2_rel + x0 @ w2_root + b2); ff split by wave.
    {
        float p = 0.f;
        const int f0 = q * 16;
        #pragma unroll
        for (int ff2 = 0; ff2 < 16; ++ff2) {
            const int ff = f0 + ff2;
            p += s_rA[ff] * w2_rel[ff * DM + lane]    // L2-resident, coalesced
               + s_rB[ff] * w2_root[ff * DM + lane];
        }
        s_pA[q][lane] = p;
    }
    __syncthreads();
    if (t < DM) {
        float y = fmaxf(s_pA[0][t] + s_pA[1][t] + s_pA[2][t] + s_pA[3][t] + b2[t], 0.f);
        s_r[t] = s_rB[t] + y;                          // x0 + y0
    }
    __syncthreads();
    if (t < 2) {
        float acc = bf[t];
        #pragma unroll
        for (int d = 0; d < DM; ++d) acc += s_r[d] * wf[d * 2 + t];
        out[b * 2 + t] = acc;
    }
}

extern "C" void kernel_launch(void* const* d_in, const int* in_sizes, int n_in,
                              void* d_out, int out_size, void* d_ws, size_t ws_size,
                              hipStream_t stream) {
    const float* adj     = (const float*)d_in[0];
    const float* vec     = (const float*)d_in[1];
    const float* w1_rel  = (const float*)d_in[2];
    const float* w1_root = (const float*)d_in[3];
    const float* b1      = (const float*)d_in[4];
    const float* w2_rel  = (const float*)d_in[5];
    const float* w2_root = (const float*)d_in[6];
    const float* b2      = (const float*)d_in[7];
    const float* wf      = (const float*)d_in[8];
    const float* bf      = (const float*)d_in[9];
    float* out = (float*)d_out;

    gnn_node0_fused<<<NB, 256, 0, stream>>>(adj, vec, w1_rel, w1_root, b1,
                                            w2_rel, w2_root, b2, wf, bf, out);
}

// Round 4
// 421.252 us; speedup vs baseline: 1.2336x; 1.1403x over previous
//
#include <hip/hip_runtime.h>
#include <hip/hip_bf16.h>

// B=1024, N=256, F=63, D=64. Only node-0 readout matters:
//   out = (x[:,0] + y[:,0]) @ wf + bf
// v4: (a) union-of-supports mask over node-0's neighbor rows, (b) coalesced
// bf16 staging of ONLY those vec rows into LDS, (c) stage-1 sparse gathers hit
// LDS not HBM (round-3's 177us was serialized ~700cy global gathers),
// (d) bf16 w1 in LDS, f32 accumulate everywhere. ~53 KB LDS -> 3 blocks/CU.

#define NB 1024
#define NN 256
#define FD 63
#define DM 64
#define MAXNBR 64   // node-0 degree cap (mean ~14, +14 sigma safe)

__launch_bounds__(256, 3)
__global__ void gnn_node0_fused(const float* __restrict__ adj,
                                const float* __restrict__ vec,
                                const float* __restrict__ w1_rel,
                                const float* __restrict__ w1_root,
                                const float* __restrict__ b1,
                                const float* __restrict__ w2_rel,
                                const float* __restrict__ w2_root,
                                const float* __restrict__ b2,
                                const float* __restrict__ wf,
                                const float* __restrict__ bf,
                                float* __restrict__ out)
{
    __shared__ __hip_bfloat16 s_vec[NN][DM];     // 32 KB, 128B-aligned rows
    __shared__ __hip_bfloat16 s_w1rel[FD][DM];   // 8 KB
    __shared__ __hip_bfloat16 s_w1root[FD][DM];  // 8 KB
    __shared__ int   s_nbr[MAXNBR];
    __shared__ float s_a0[MAXNBR];
    __shared__ unsigned int s_umask[8];          // 256-bit union of supports
    __shared__ unsigned short s_rows[NN];        // compacted union row list
    __shared__ float s_pA[4][DM], s_pB[4][DM];
    __shared__ float s_rA[DM], s_rB[DM], s_r[DM];
    __shared__ int   s_cnt, s_rcnt;

    const int b = blockIdx.x, t = threadIdx.x;
    const int lane = t & 63, q = t >> 6;
    const float* adj_b = adj + (size_t)b * NN * NN;
    const float* vec_b = vec + (size_t)b * NN * FD;

    if (t == 0) { s_cnt = 0; s_rcnt = 0; }
    if (t < 8) s_umask[t] = 0u;
    __syncthreads();

    // ---- adj row 0 -> neighbor compaction (unordered; accumulation commutes)
    {
        float a = adj_b[t];
        if (a != 0.f) {
            int idx = atomicAdd(&s_cnt, 1);
            if (idx < MAXNBR) { s_nbr[idx] = t; s_a0[idx] = a; }
        }
    }
    // ---- stage w1 weights to LDS (bf16), coalesced
    for (int i = t; i < FD * DM; i += 256) {
        (&s_w1rel[0][0])[i]  = __float2bfloat16(w1_rel[i]);
        (&s_w1root[0][0])[i] = __float2bfloat16(w1_root[i]);
    }
    __syncthreads();

    const int cnt = min(s_cnt, MAXNBR);          // >=1 (self-loop at node 0)

    // ---- union-of-supports mask: wave q scans rows i=q,q+4,... (warms L2)
    for (int i = q; i < cnt; i += 4) {
        const float* rp = adj_b + (size_t)s_nbr[i] * NN;
        #pragma unroll
        for (int c = 0; c < 4; ++c) {
            const float av = rp[c * 64 + lane];
            const unsigned long long m = __ballot(av != 0.f);
            if (lane == 0) {
                const unsigned int lo = (unsigned int)m;
                const unsigned int hi = (unsigned int)(m >> 32);
                if (lo) atomicOr(&s_umask[c * 2],     lo);
                if (hi) atomicOr(&s_umask[c * 2 + 1], hi);
            }
        }
    }
    __syncthreads();

    // ---- compact union rows (unordered)
    if ((s_umask[t >> 5] >> (t & 31)) & 1u) {
        int p = atomicAdd(&s_rcnt, 1);
        s_rows[p] = (unsigned short)t;
    }
    __syncthreads();

    // ---- stream union vec rows -> LDS bf16, 4-deep pipelined, coalesced
    const int rcnt = s_rcnt;
    for (int p = q; p < rcnt; p += 16) {
        const int p1 = p + 4, p2 = p + 8, p3 = p + 12;
        const int r0 = s_rows[p];
        const int r1 = s_rows[p1 < rcnt ? p1 : p];
        const int r2 = s_rows[p2 < rcnt ? p2 : p];
        const int r3 = s_rows[p3 < rcnt ? p3 : p];
        float v0 = 0.f, v1 = 0.f, v2 = 0.f, v3 = 0.f;
        if (lane < FD) {                          // 4 independent loads in flight
            v0 = vec_b[r0 * FD + lane];
            v1 = vec_b[r1 * FD + lane];
            v2 = vec_b[r2 * FD + lane];
            v3 = vec_b[r3 * FD + lane];
        }
        s_vec[r0][lane] = __float2bfloat16(v0);   // lane 63 -> 0 pad
        if (p1 < rcnt) s_vec[r1][lane] = __float2bfloat16(v1);
        if (p2 < rcnt) s_vec[r2][lane] = __float2bfloat16(v2);
        if (p3 < rcnt) s_vec[r3][lane] = __float2bfloat16(v3);
    }
    __syncthreads();

    // ---- main loop: wave q owns neighbors i=q,q+4,...; no barriers.
    const float rb1 = b1[lane];
    float accY = 0.f, x0r = 0.f;

    int i = q;
    int jcur = (i < cnt) ? s_nbr[i] : 0;
    float c0 = 0.f, c1 = 0.f, c2 = 0.f, c3 = 0.f;
    if (i < cnt) {                                 // L2-warm reload
        const float* rp = adj_b + (size_t)jcur * NN;
        c0 = rp[lane]; c1 = rp[64 + lane]; c2 = rp[128 + lane]; c3 = rp[192 + lane];
    }
    while (i < cnt) {
        const int inext = i + 4;
        int jnext = 0; float n0 = 0.f, n1 = 0.f, n2 = 0.f, n3 = 0.f;
        if (inext < cnt) {                         // prefetch next row
            jnext = s_nbr[inext];
            const float* rp = adj_b + (size_t)jnext * NN;
            n0 = rp[lane]; n1 = rp[64 + lane]; n2 = rp[128 + lane]; n3 = rp[192 + lane];
        }
        // Stage 1 (sparse, all from LDS): agg[f=lane] = sum_k a_k * vec[k][f]
        float agg = 0.f;
        {
            unsigned long long m;
            m = __ballot(c0 != 0.f);
            while (m) { int bb = __builtin_ctzll(m); m &= m - 1;
                        agg += __shfl(c0, bb) * __bfloat162float(s_vec[bb][lane]); }
            m = __ballot(c1 != 0.f);
            while (m) { int bb = __builtin_ctzll(m); m &= m - 1;
                        agg += __shfl(c1, bb) * __bfloat162float(s_vec[64 + bb][lane]); }
            m = __ballot(c2 != 0.f);
            while (m) { int bb = __builtin_ctzll(m); m &= m - 1;
                        agg += __shfl(c2, bb) * __bfloat162float(s_vec[128 + bb][lane]); }
            m = __ballot(c3 != 0.f);
            while (m) { int bb = __builtin_ctzll(m); m &= m - 1;
                        agg += __shfl(c3, bb) * __bfloat162float(s_vec[192 + bb][lane]); }
        }
        // Stage 2: x[d=lane] = relu(agg @ w1_rel + vec_j @ w1_root + b1)
        const float vj = __bfloat162float(s_vec[jcur][lane]);
        float accR = 0.f, accO = 0.f;
        #pragma unroll
        for (int ff = 0; ff < FD; ++ff) {
            accR += __shfl(agg, ff) * __bfloat162float(s_w1rel[ff][lane]);
            accO += __shfl(vj,  ff) * __bfloat162float(s_w1root[ff][lane]);
        }
        const float x = fmaxf(accR + accO + rb1, 0.f);
        accY += s_a0[i] * x;
        if (jcur == 0) x0r = x;

        i = inext; jcur = jnext;
        c0 = n0; c1 = n1; c2 = n2; c3 = n3;
    }

    // ---- cross-wave reduction of accY and x0
    s_pA[q][lane] = accY;
    s_pB[q][lane] = x0r;
    __syncthreads();
    if (q == 0) {
        s_rA[lane] = s_pA[0][lane] + s_pA[1][lane] + s_pA[2][lane] + s_pA[3][lane];
        s_rB[lane] = s_pB[0][lane] + s_pB[1][lane] + s_pB[2][lane] + s_pB[3][lane];
    }
    __syncthreads();

    // ---- layer 2 row 0: y0 = relu(accY @ w2_rel + x0 @ w2_root + b2)
    {
        float p = 0.f;
        const int f0 = q * 16;
        #pragma unroll
        for (int ff2 = 0; ff2 < 16; ++ff2) {
            const int ff = f0 + ff2;
            p += s_rA[ff] * w2_rel[ff * DM + lane]     // f32, L2-resident
               + s_rB[ff] * w2_root[ff * DM + lane];
        }
        s_pA[q][lane] = p;
    }
    __syncthreads();
    if (t < DM) {
        float y = fmaxf(s_pA[0][t] + s_pA[1][t] + s_pA[2][t] + s_pA[3][t] + b2[t], 0.f);
        s_r[t] = s_rB[t] + y;                          // x0 + y0
    }
    __syncthreads();
    if (t < 2) {
        float acc = bf[t];
        #pragma unroll
        for (int d = 0; d < DM; ++d) acc += s_r[d] * wf[d * 2 + t];
        out[b * 2 + t] = acc;
    }
}

extern "C" void kernel_launch(void* const* d_in, const int* in_sizes, int n_in,
                              void* d_out, int out_size, void* d_ws, size_t ws_size,
                              hipStream_t stream) {
    const float* adj     = (const float*)d_in[0];
    const float* vec     = (const float*)d_in[1];
    const float* w1_rel  = (const float*)d_in[2];
    const float* w1_root = (const float*)d_in[3];
    const float* b1      = (const float*)d_in[4];
    const float* w2_rel  = (const float*)d_in[5];
    const float* w2_root = (const float*)d_in[6];
    const float* b2      = (const float*)d_in[7];
    const float* wf      = (const float*)d_in[8];
    const float* bf      = (const float*)d_in[9];
    float* out = (float*)d_out;

    gnn_node0_fused<<<NB, 256, 0, stream>>>(adj, vec, w1_rel, w1_root, b1,
                                            w2_rel, w2_root, b2, wf, bf, out);
}